// Round 1
// baseline (701.100 us; speedup 1.0000x reference)
//
#include <hip/hip_runtime.h>
#include <math.h>

#define NT    1100
#define DM    640
#define WSTR  1104   // padded row stride (floats/doubles) for the 1100-wide matrices
#define NSUP  100
#define TOPKK 10

// ---------------- K1: spatial mean (f64 accum) ----------------
// rows = n*640+d, each row = 100 contiguous f32. 32 lanes per row, 8 rows/block.
__global__ __launch_bounds__(256) void k_mean(const float* __restrict__ sup,
                                              const float* __restrict__ qry,
                                              double* __restrict__ x) {
  int row  = blockIdx.x * 8 + (threadIdx.x >> 5);
  int lane = threadIdx.x & 31;
  const float* src = (row < NSUP * DM) ? sup + (size_t)row * 100
                                       : qry + (size_t)(row - NSUP * DM) * 100;
  double s = 0.0;
#pragma unroll
  for (int i = 0; i < 4; ++i) {
    int j = lane + i * 32;
    if (j < 100) s += (double)src[j];
  }
#pragma unroll
  for (int off = 16; off; off >>= 1) s += __shfl_down(s, off, 32);
  if (lane == 0) x[row] = s * 0.01;
}

// ---------------- K2a: emb_q = x @ Wq^T  (f64) ----------------
// NT-gemm: A[M,K] f64, B[N,K] f32(Wq row-major [out,in]), C[M,N] f64
__global__ __launch_bounds__(256) void k_embq(const double* __restrict__ x,
                                              const float* __restrict__ Wq,
                                              double* __restrict__ eq) {
  __shared__ __align__(16) double As[16][64];
  __shared__ __align__(16) double Bs[16][64];
  int m0 = blockIdx.y * 64, n0 = blockIdx.x * 64;
  int t = threadIdx.x;
  int lm = t >> 2, lk = (t & 3) * 4;
  int ty = t >> 4, tx = t & 15;
  double acc[4][4] = {};
  for (int k0 = 0; k0 < DM; k0 += 16) {
    double a0 = 0, a1 = 0, a2 = 0, a3 = 0;
    if (m0 + lm < NT) {
      const double* p = x + (size_t)(m0 + lm) * DM + k0 + lk;
      a0 = p[0]; a1 = p[1]; a2 = p[2]; a3 = p[3];
    }
    As[lk + 0][lm] = a0; As[lk + 1][lm] = a1; As[lk + 2][lm] = a2; As[lk + 3][lm] = a3;
    const float4 bv = *(const float4*)(Wq + (size_t)(n0 + lm) * DM + k0 + lk);
    Bs[lk + 0][lm] = (double)bv.x; Bs[lk + 1][lm] = (double)bv.y;
    Bs[lk + 2][lm] = (double)bv.z; Bs[lk + 3][lm] = (double)bv.w;
    __syncthreads();
#pragma unroll
    for (int k = 0; k < 16; ++k) {
      double a[4], b[4];
      *(double2*)&a[0] = *(const double2*)&As[k][ty * 4];
      *(double2*)&a[2] = *(const double2*)&As[k][ty * 4 + 2];
      *(double2*)&b[0] = *(const double2*)&Bs[k][tx * 4];
      *(double2*)&b[2] = *(const double2*)&Bs[k][tx * 4 + 2];
#pragma unroll
      for (int i = 0; i < 4; ++i)
#pragma unroll
        for (int j = 0; j < 4; ++j) acc[i][j] = fma(a[i], b[j], acc[i][j]);
    }
    __syncthreads();
  }
#pragma unroll
  for (int i = 0; i < 4; ++i) {
    int r = m0 + ty * 4 + i;
    if (r < NT) {
      double* c = eq + (size_t)r * DM + n0 + tx * 4;
      c[0] = acc[i][0]; c[1] = acc[i][1]; c[2] = acc[i][2]; c[3] = acc[i][3];
    }
  }
}

// ---------------- K2b: emb_v = x @ Wv^T  (f32) ----------------
__global__ __launch_bounds__(256) void k_embv(const double* __restrict__ x,
                                              const float* __restrict__ Wv,
                                              float* __restrict__ ev) {
  __shared__ __align__(16) float As[16][64];
  __shared__ __align__(16) float Bs[16][64];
  int m0 = blockIdx.y * 64, n0 = blockIdx.x * 64;
  int t = threadIdx.x;
  int lm = t >> 2, lk = (t & 3) * 4;
  int ty = t >> 4, tx = t & 15;
  float acc[4][4] = {};
  for (int k0 = 0; k0 < DM; k0 += 16) {
    float a0 = 0, a1 = 0, a2 = 0, a3 = 0;
    if (m0 + lm < NT) {
      const double* p = x + (size_t)(m0 + lm) * DM + k0 + lk;
      a0 = (float)p[0]; a1 = (float)p[1]; a2 = (float)p[2]; a3 = (float)p[3];
    }
    As[lk + 0][lm] = a0; As[lk + 1][lm] = a1; As[lk + 2][lm] = a2; As[lk + 3][lm] = a3;
    const float4 bv = *(const float4*)(Wv + (size_t)(n0 + lm) * DM + k0 + lk);
    Bs[lk + 0][lm] = bv.x; Bs[lk + 1][lm] = bv.y; Bs[lk + 2][lm] = bv.z; Bs[lk + 3][lm] = bv.w;
    __syncthreads();
#pragma unroll
    for (int k = 0; k < 16; ++k) {
      float4 a = *(const float4*)&As[k][ty * 4];
      float4 b = *(const float4*)&Bs[k][tx * 4];
      acc[0][0] = fmaf(a.x, b.x, acc[0][0]); acc[0][1] = fmaf(a.x, b.y, acc[0][1]);
      acc[0][2] = fmaf(a.x, b.z, acc[0][2]); acc[0][3] = fmaf(a.x, b.w, acc[0][3]);
      acc[1][0] = fmaf(a.y, b.x, acc[1][0]); acc[1][1] = fmaf(a.y, b.y, acc[1][1]);
      acc[1][2] = fmaf(a.y, b.z, acc[1][2]); acc[1][3] = fmaf(a.y, b.w, acc[1][3]);
      acc[2][0] = fmaf(a.z, b.x, acc[2][0]); acc[2][1] = fmaf(a.z, b.y, acc[2][1]);
      acc[2][2] = fmaf(a.z, b.z, acc[2][2]); acc[2][3] = fmaf(a.z, b.w, acc[2][3]);
      acc[3][0] = fmaf(a.w, b.x, acc[3][0]); acc[3][1] = fmaf(a.w, b.y, acc[3][1]);
      acc[3][2] = fmaf(a.w, b.z, acc[3][2]); acc[3][3] = fmaf(a.w, b.w, acc[3][3]);
    }
    __syncthreads();
  }
#pragma unroll
  for (int i = 0; i < 4; ++i) {
    int r = m0 + ty * 4 + i;
    if (r < NT) *(float4*)(ev + (size_t)r * DM + n0 + tx * 4) =
        make_float4(acc[i][0], acc[i][1], acc[i][2], acc[i][3]);
  }
}

// zero the 4 pad rows of ev (rows 1100..1103)
__global__ void k_evpad(float* __restrict__ ev) {
  int t = blockIdx.x * 256 + threadIdx.x;
  if (t < 4 * DM) ev[(size_t)NT * DM + t] = 0.f;
}

// ---------------- K3: row squared norms of emb_q (f64) ----------------
__global__ void k_sq(const double* __restrict__ eq, double* __restrict__ sq) {
  int r = blockIdx.x, lane = threadIdx.x;  // 64 threads
  const double* p = eq + (size_t)r * DM;
  double s = 0;
  for (int i = lane; i < DM; i += 64) s = fma(p[i], p[i], s);
#pragma unroll
  for (int off = 32; off; off >>= 1) s += __shfl_down(s, off);
  if (!lane) sq[r] = s;
}

// ---------------- K4: gram + raw distances (f64) + global sum/sumsq ----------------
__global__ __launch_bounds__(256) void k_dist(const double* __restrict__ eq,
                                              const double* __restrict__ sq,
                                              double* __restrict__ w,
                                              double* __restrict__ sums) {
  __shared__ __align__(16) double As[16][64];
  __shared__ __align__(16) double Bs[16][64];
  __shared__ double red[256];
  int m0 = blockIdx.y * 64, n0 = blockIdx.x * 64;
  int t = threadIdx.x;
  int lm = t >> 2, lk = (t & 3) * 4;
  int ty = t >> 4, tx = t & 15;
  double acc[4][4] = {};
  for (int k0 = 0; k0 < DM; k0 += 16) {
    double a0 = 0, a1 = 0, a2 = 0, a3 = 0;
    if (m0 + lm < NT) {
      const double* p = eq + (size_t)(m0 + lm) * DM + k0 + lk;
      a0 = p[0]; a1 = p[1]; a2 = p[2]; a3 = p[3];
    }
    As[lk + 0][lm] = a0; As[lk + 1][lm] = a1; As[lk + 2][lm] = a2; As[lk + 3][lm] = a3;
    double b0 = 0, b1 = 0, b2 = 0, b3 = 0;
    if (n0 + lm < NT) {
      const double* p = eq + (size_t)(n0 + lm) * DM + k0 + lk;
      b0 = p[0]; b1 = p[1]; b2 = p[2]; b3 = p[3];
    }
    Bs[lk + 0][lm] = b0; Bs[lk + 1][lm] = b1; Bs[lk + 2][lm] = b2; Bs[lk + 3][lm] = b3;
    __syncthreads();
#pragma unroll
    for (int k = 0; k < 16; ++k) {
      double a[4], b[4];
      *(double2*)&a[0] = *(const double2*)&As[k][ty * 4];
      *(double2*)&a[2] = *(const double2*)&As[k][ty * 4 + 2];
      *(double2*)&b[0] = *(const double2*)&Bs[k][tx * 4];
      *(double2*)&b[2] = *(const double2*)&Bs[k][tx * 4 + 2];
#pragma unroll
      for (int i = 0; i < 4; ++i)
#pragma unroll
        for (int j = 0; j < 4; ++j) acc[i][j] = fma(a[i], b[j], acc[i][j]);
    }
    __syncthreads();
  }
  double ls1 = 0, ls2 = 0;
#pragma unroll
  for (int i = 0; i < 4; ++i) {
    int r = m0 + ty * 4 + i;
#pragma unroll
    for (int j = 0; j < 4; ++j) {
      int c = n0 + tx * 4 + j;
      if (r < NT && c < NT) {
        double v = 0.0;
        if (r != c) {
          v = sq[r] + sq[c] - 2.0 * acc[i][j];
          v = v > 0.0 ? v : 0.0;
          ls1 += v;
          ls2 = fma(v, v, ls2);
        }
        w[(size_t)r * WSTR + c] = v;
      }
    }
  }
  red[t] = ls1; __syncthreads();
  for (int s = 128; s; s >>= 1) { if (t < s) red[t] += red[t + s]; __syncthreads(); }
  if (!t) atomicAdd(&sums[0], red[0]);
  __syncthreads();
  red[t] = ls2; __syncthreads();
  for (int s = 128; s; s >>= 1) { if (t < s) red[t] += red[t + s]; __syncthreads(); }
  if (!t) atomicAdd(&sums[1], red[0]);
}

// ---------------- K5: finalize scale = -0.5/std ----------------
__global__ void k_scal(double* __restrict__ sums) {
  double cnt = (double)NT * NT - NT;
  double mean = sums[0] / cnt;
  double var = (sums[1] - sums[0] * mean) / (cnt - 1.0);
  sums[2] = -0.5 / sqrt(var);
}

// ---------------- K6: per-row exp (f32 out) + top-10 (on f64 raw, argmin) ----------------
__global__ __launch_bounds__(256) void k_topk(const double* __restrict__ w64,
                                              const double* __restrict__ sums,
                                              float* __restrict__ wf,
                                              int* __restrict__ idx) {
  __shared__ double vals[NT];
  __shared__ double bv[256];
  __shared__ int    bi[256];
  int i = blockIdx.x, t = threadIdx.x;
  double sc = sums[2];
  const double* wr = w64 + (size_t)i * WSTR;
  float* wo = wf + (size_t)i * WSTR;
  for (int j = t; j < WSTR; j += 256) {
    if (j < NT) {
      double v = wr[j];
      vals[j] = v;
      wo[j] = (float)exp(v * sc);
    } else wo[j] = 0.f;
  }
  __syncthreads();
  for (int k = 0; k < TOPKK; ++k) {
    double best = 1.0e300; int bidx = NT;
    for (int j = t; j < NT; j += 256) {
      double v = vals[j];
      if (v < best || (v == best && j < bidx)) { best = v; bidx = j; }
    }
    bv[t] = best; bi[t] = bidx; __syncthreads();
    for (int s = 128; s; s >>= 1) {
      if (t < s) {
        if (bv[t + s] < bv[t] || (bv[t + s] == bv[t] && bi[t + s] < bi[t])) {
          bv[t] = bv[t + s]; bi[t] = bi[t + s];
        }
      }
      __syncthreads();
    }
    if (!t) { idx[i * TOPKK + k] = bi[0]; vals[bi[0]] = 1.0e301; }
    __syncthreads();
  }
}

// ---------------- K7: scatter mask ----------------
__global__ void k_scatter(const int* __restrict__ idx, unsigned char* __restrict__ mask) {
  int e = blockIdx.x * 256 + threadIdx.x;
  if (e < NT * TOPKK) {
    int i = e / TOPKK;
    mask[(size_t)i * NT + idx[e]] = 1;
  }
}

// ---------------- K8: symmetric mask apply + degree ----------------
__global__ __launch_bounds__(256) void k_maskdeg(const unsigned char* __restrict__ mask,
                                                 float* __restrict__ wf,
                                                 float* __restrict__ deg) {
  __shared__ float red[256];
  int i = blockIdx.x, t = threadIdx.x;
  float s = 0;
  for (int j = t; j < WSTR; j += 256) {
    float wm = 0.f;
    if (j < NT) {
      if (mask[(size_t)i * NT + j] | mask[(size_t)j * NT + i]) wm = wf[(size_t)i * WSTR + j];
    }
    wf[(size_t)i * WSTR + j] = wm;
    s += wm;
  }
  red[t] = s; __syncthreads();
  for (int st = 128; st; st >>= 1) { if (t < st) red[t] += red[t + st]; __syncthreads(); }
  if (!t) deg[i] = red[0];
}

// ---------------- K9: dsi = sqrt(1/(deg+eps)), zero-padded to WSTR ----------------
__global__ void k_dsi(const float* __restrict__ deg, float* __restrict__ dsi) {
  int i = blockIdx.x * 256 + threadIdx.x;
  if (i < WSTR)
    dsi[i] = (i < NT) ? (float)sqrt(1.0 / ((double)deg[i] + 2.220446049250313e-16)) : 0.f;
}

// ---------------- K10: out = (dsi_i * w_ij * dsi_j) @ emb_v  (f32 NN-gemm) ----------------
__global__ __launch_bounds__(256) void k_out(const float* __restrict__ wf,
                                             const float* __restrict__ ev,
                                             const float* __restrict__ dsi,
                                             float* __restrict__ out) {
  __shared__ __align__(16) float As[16][64];
  __shared__ __align__(16) float Bs[16][64];
  int m0 = blockIdx.y * 64, n0 = blockIdx.x * 64;
  int t = threadIdx.x;
  int lm = t >> 2, lk = (t & 3) * 4;   // A staging
  int kr = t >> 4, nn = (t & 15) * 4;  // B staging
  int ty = t >> 4, tx = t & 15;
  float acc[4][4] = {};
  for (int k0 = 0; k0 < WSTR; k0 += 16) {
    float4 av = make_float4(0, 0, 0, 0);
    if (m0 + lm < NT) av = *(const float4*)(wf + (size_t)(m0 + lm) * WSTR + k0 + lk);
    As[lk + 0][lm] = av.x * dsi[k0 + lk + 0];
    As[lk + 1][lm] = av.y * dsi[k0 + lk + 1];
    As[lk + 2][lm] = av.z * dsi[k0 + lk + 2];
    As[lk + 3][lm] = av.w * dsi[k0 + lk + 3];
    *(float4*)&Bs[kr][nn] = *(const float4*)(ev + (size_t)(k0 + kr) * DM + n0 + nn);
    __syncthreads();
#pragma unroll
    for (int k = 0; k < 16; ++k) {
      float4 a = *(const float4*)&As[k][ty * 4];
      float4 b = *(const float4*)&Bs[k][tx * 4];
      acc[0][0] = fmaf(a.x, b.x, acc[0][0]); acc[0][1] = fmaf(a.x, b.y, acc[0][1]);
      acc[0][2] = fmaf(a.x, b.z, acc[0][2]); acc[0][3] = fmaf(a.x, b.w, acc[0][3]);
      acc[1][0] = fmaf(a.y, b.x, acc[1][0]); acc[1][1] = fmaf(a.y, b.y, acc[1][1]);
      acc[1][2] = fmaf(a.y, b.z, acc[1][2]); acc[1][3] = fmaf(a.y, b.w, acc[1][3]);
      acc[2][0] = fmaf(a.z, b.x, acc[2][0]); acc[2][1] = fmaf(a.z, b.y, acc[2][1]);
      acc[2][2] = fmaf(a.z, b.z, acc[2][2]); acc[2][3] = fmaf(a.z, b.w, acc[2][3]);
      acc[3][0] = fmaf(a.w, b.x, acc[3][0]); acc[3][1] = fmaf(a.w, b.y, acc[3][1]);
      acc[3][2] = fmaf(a.w, b.z, acc[3][2]); acc[3][3] = fmaf(a.w, b.w, acc[3][3]);
    }
    __syncthreads();
  }
#pragma unroll
  for (int i = 0; i < 4; ++i) {
    int r = m0 + ty * 4 + i;
    if (r < NT) {
      float s = dsi[r];
      *(float4*)(out + (size_t)r * DM + n0 + tx * 4) =
          make_float4(acc[i][0] * s, acc[i][1] * s, acc[i][2] * s, acc[i][3] * s);
    }
  }
}

extern "C" void kernel_launch(void* const* d_in, const int* in_sizes, int n_in,
                              void* d_out, int out_size, void* d_ws, size_t ws_size,
                              hipStream_t stream) {
  const float* sup = (const float*)d_in[0];
  const float* qry = (const float*)d_in[2];
  const float* Wq  = (const float*)d_in[4];
  const float* Wv  = (const float*)d_in[5];
  float* out = (float*)d_out;

  char* ws = (char*)d_ws;
  // workspace layout (all offsets 16B-aligned); total ~29.9 MB
  double* x64 = (double*)(ws + 0);          // 704000 f64
  double* eq  = (double*)(ws + 5632000);    // 704000 f64
  float*  ev  = (float*) (ws + 11264000);   // 1104*640 f32 (4 pad rows)
  double* w64 = (double*)(ws + 14090240);   // 1100*1104 f64 raw distances
  float*  wf  = (float*) (ws + 23805440);   // 1100*1104 f32 exp'd/masked
  double* sq  = (double*)(ws + 28663040);   // 1100 f64
  float*  deg = (float*) (ws + 28671840);   // 1100 f32
  float*  dsi = (float*) (ws + 28676240);   // 1104 f32
  int*    idx = (int*)   (ws + 28680656);   // 11000 int
  double* sums= (double*)(ws + 28724656);   // [S1, S2, scale]
  unsigned char* mask = (unsigned char*)(ws + 28724688); // 1100*1100 u8

  hipMemsetAsync(sums, 0, 32, stream);
  hipMemsetAsync(mask, 0, (size_t)NT * NT, stream);

  k_mean<<<dim3((NT * DM) / 8), 256, 0, stream>>>(sup, qry, x64);
  k_embq<<<dim3(DM / 64, 18), 256, 0, stream>>>(x64, Wq, eq);
  k_embv<<<dim3(DM / 64, 18), 256, 0, stream>>>(x64, Wv, ev);
  k_evpad<<<dim3(10), 256, 0, stream>>>(ev);
  k_sq<<<dim3(NT), 64, 0, stream>>>(eq, sq);
  k_dist<<<dim3(18, 18), 256, 0, stream>>>(eq, sq, w64, sums);
  k_scal<<<dim3(1), 1, 0, stream>>>(sums);
  k_topk<<<dim3(NT), 256, 0, stream>>>(w64, sums, wf, idx);
  k_scatter<<<dim3(43), 256, 0, stream>>>(idx, mask);
  k_maskdeg<<<dim3(NT), 256, 0, stream>>>(mask, wf, deg);
  k_dsi<<<dim3(5), 256, 0, stream>>>(deg, dsi);
  k_out<<<dim3(DM / 64, 18), 256, 0, stream>>>(wf, ev, dsi, out);
}